// Round 4
// baseline (29.055 us; speedup 1.0000x reference)
//
#include <hip/hip_runtime.h>

#define C 256
#define HW 81
#define XP 268   // dwords per pixel row of xk1: [4 pad][256 ch][8 pad]; mult of 4 for b128
#define VP 270   // ushorts per row of vT: [4 pad][256 ch][10 pad]
#define ZROW 81  // zeroed row index for invalid gather taps

__device__ __forceinline__ float lo_f(unsigned int d) {
  union { unsigned int i; float f; } c; c.i = d << 16; return c.f;
}
__device__ __forceinline__ float hi_f(unsigned int d) {
  union { unsigned int i; float f; } c; c.i = d & 0xffff0000u; return c.f;
}
__device__ __forceinline__ float bf2f(unsigned short u) {
  union { unsigned int i; float f; } c; c.i = ((unsigned int)u) << 16; return c.f;
}
__device__ __forceinline__ unsigned short f2bf(float f) {
  union { float f; unsigned int i; } c; c.f = f;
  return (unsigned short)((c.i + 0x7fffu + ((c.i >> 16) & 1u)) >> 16);
}

// ---------------------------------------------------------------------------
// Fully fused SeMCA. Block = (b, s): s=0 -> output rows 0..5, s=1 -> rows 6..8.
// 1024 threads = 4 instance-slots x 256 channels. 2 barriers.
// R4 (theory: exposed LDS-gather latency chains):
//  - xk1 interleaved layout: one dword per (pixel, channel), lo16 = x bf16,
//    hi16 = k1 bf16. Phase-2 gather reads HALVE (9 ds_read_b32 yield both the
//    x-part and k1-part of kq), and each read feeds two FMA streams.
//  - 1-deep instance prefetch: instance k+1's 9 gather dwords issue before
//    instance k's w1/w2/softmax compute (issue-early, static indexing).
//  - phase-1a: 3x ds_read_b128 + 1x ds_write_b128 per 4-channel quad; the
//    write reproduces lo16 (x) bit-exactly so concurrent halo readers and
//    phase-1b (which reads lo16 only) are unaffected.
//  - LDS ~97.5 KiB (xk1 87.9K + vT 9.7K + tabs).
// ---------------------------------------------------------------------------
__global__ __launch_bounds__(1024) void semca_fused(
    const float* __restrict__ x, const float* __restrict__ wk,
    const float* __restrict__ bk, const float* __restrict__ w1,
    const float* __restrict__ gamma, const float* __restrict__ beta,
    const float* __restrict__ mean, const float* __restrict__ var,
    const float* __restrict__ w2, const float* __restrict__ b2,
    const float* __restrict__ wv, const float* __restrict__ bv,
    float* __restrict__ out) {
  __shared__ unsigned int xk1[82 * XP];     // 87,904 B (row 81 = zeros)
  __shared__ unsigned short vT[18 * VP];    //  9,720 B
  __shared__ unsigned short pixtab[228];    //    456 B (premultiplied by XP)
  __shared__ float2 bnf[225];               //  1,800 B  (~97.5 KiB total)

  const int blk = blockIdx.x;
  const int b = (blk & 7) * 16 + ((blk >> 3) & 15);  // XCD-paired, bijective
  const int s = blk >> 7;
  const int tid = threadIdx.x;
  const float* xb = x + (size_t)b * (C * HW);

  // ---- phase 0: stage x into lo16 (hi16=0), tables, zeros
  {
    auto stage = [&](int f) {
      int c = f / HW;              // channel 0..255 (p consecutive per lane)
      int p = f - c * HW;
      xk1[XP * p + 4 + c] = (unsigned int)f2bf(xb[c * HW + p]);
    };
#pragma unroll
    for (int rep = 0; rep < 20; ++rep) stage(tid + rep * 1024);
    if (tid < 256) stage(20480 + tid);
  }
  for (int t = tid; t < 1240; t += 1024) {  // pads + zero row 81
    if (t < 972) {
      int row = t / 12, j = t - row * 12;
      xk1[XP * row + ((j < 4) ? j : (256 + j))] = 0;
    } else {
      xk1[XP * ZROW + (t - 972)] = 0;
    }
  }
  if (tid < 144) {  // vT channel-pad zeros (cols 0..3, 260..263)
    int e = tid >> 3, j = tid & 7;
    vT[VP * e + ((j < 4) ? j : (256 + j))] = 0;
  }
  for (int t = tid; t < 225; t += 1024) {  // pixtab (premul XP) + folded BN
    int g = t / 9, tap = t - (t / 9) * 9;
    int kh = tap / 3, kw = tap - kh * 3;
    int h = kh * 5 + g / 5, w = kw * 5 + (g - (g / 5) * 5);
    pixtab[t] = (h < 9 && w < 9) ? (unsigned short)((h * 9 + w) * XP)
                                 : (unsigned short)(ZROW * XP);
    float inv = gamma[t] * rsqrtf(var[t] + 1e-5f);
    bnf[t] = make_float2(inv, beta[t] - mean[t] * inv);
  }

  // ---- hoisted phase-1b weights: channel (tid&255) fixed per thread
  const int chv = tid & 255;
  float wvc[9];
#pragma unroll
  for (int t = 0; t < 9; ++t) wvc[t] = wv[chv * 9 + t];
  const float bvc = bv[chv];

  __syncthreads();

  // ---- phase 1a: k1[p][c] = sum_j x[p][c+j-4]*wk[p][j] + bk[p] -> hi16
  // quad u: channels 4u..4u+3 from dwords XP*p+4u..+11 (halo via pads),
  // 3x b128 read; 1x b128 write rebuilding lo16 bit-exactly.
  {
    auto k1fn = [&](int f) {
      int p = __builtin_amdgcn_readfirstlane(f >> 6);
      int u = f & 63;
      const uint4* W = (const uint4*)(xk1 + XP * p + 4 * u);
      uint4 A = W[0], B = W[1], Cq = W[2];
      float e[12] = {lo_f(A.x), lo_f(A.y), lo_f(A.z), lo_f(A.w),
                     lo_f(B.x), lo_f(B.y), lo_f(B.z), lo_f(B.w),
                     lo_f(Cq.x), lo_f(Cq.y), lo_f(Cq.z), lo_f(Cq.w)};
      const float* wkp = wk + p * 9;  // scalar loads (p uniform)
      float bkp = bk[p];
      float c0 = bkp, c1 = bkp, c2 = bkp, c3 = bkp;
#pragma unroll
      for (int j = 0; j < 9; ++j) {
        float wj = wkp[j];
        c0 = fmaf(wj, e[j], c0);
        c1 = fmaf(wj, e[j + 1], c1);
        c2 = fmaf(wj, e[j + 2], c2);
        c3 = fmaf(wj, e[j + 3], c3);
      }
      uint4 o;
      o.x = (B.x & 0xffffu) | ((unsigned int)f2bf(c0) << 16);
      o.y = (B.y & 0xffffu) | ((unsigned int)f2bf(c1) << 16);
      o.z = (B.z & 0xffffu) | ((unsigned int)f2bf(c2) << 16);
      o.w = (B.w & 0xffffu) | ((unsigned int)f2bf(c3) << 16);
      *(uint4*)(xk1 + XP * p + 4 + 4 * u) = o;
    };
#pragma unroll
    for (int rep = 0; rep < 5; ++rep) k1fn(tid + rep * 1024);
    if (tid < 64) k1fn(5120 + tid);
  }

  // ---- phase 1b: v (3x3 depthwise) at the 18 pixels this half needs
  {
    auto vfn = [&](int f) {
      int e = __builtin_amdgcn_readfirstlane(f >> 8);  // 0..17 uniform
      int r0 = e / 6;
      int i = s * 3 + r0;  // v-pixel row 0..5
      int j = e - r0 * 6;  // v-pixel col 0..5
      float a = bvc;
#pragma unroll
      for (int di = 0; di < 3; ++di) {
        int ii = i + di - 1;
        if (ii < 0) continue;  // ii <= 6 < 9 always
#pragma unroll
        for (int dj = 0; dj < 3; ++dj) {
          int jj = j + dj - 1;
          if (jj < 0) continue;  // jj <= 6 < 9 always
          unsigned int d = xk1[XP * (ii * 9 + jj) + 4 + chv];
          a = fmaf(lo_f(d), wvc[di * 3 + dj], a);
        }
      }
      vT[VP * e + 4 + chv] = f2bf(a);
    };
#pragma unroll
    for (int rep = 0; rep < 4; ++rep) vfn(tid + rep * 1024);
    if (tid < 512) vfn(4096 + tid);
  }
  __syncthreads();

  // ---- phase 2: 15 deduped instances; 4 slots x 4 unrolled iterations
  const int s4 = tid >> 8;  // slot 0..3 (wave-uniform)
  const int ch = tid & 255;
  const int ci0 = ch / 9;
  const int tap0 = ch - ci0 * 9;
  float* outb = out + ((size_t)b * C + ch) * HW;

  // per-lane gather walk is instance-invariant (t_q = ch + 256q)
  int tq[9], cq[9];
  {
    int ci = ci0, tap = tap0;
#pragma unroll
    for (int q = 0; q < 9; ++q) {
      tq[q] = tap;
      cq[q] = 4 + ci;
      tap += 4;
      ci += 28;
      if (tap >= 9) { tap -= 9; ci += 1; }
    }
  }

  // instance parameters, computed upfront
  int g9s[4], ohs[4], ghis[4], gwis[4];
  bool valids[4];
#pragma unroll
  for (int k = 0; k < 4; ++k) {
    int idx = s4 * 4 + k;
    valids[k] = (idx < 15);
    if (idx >= 15) idx = 14;  // dummy recomputes a real instance, no store
    int gh_i = idx / 5, gw_i = idx - (idx / 5) * 5;
    ghis[k] = gh_i;
    gwis[k] = gw_i;
    ohs[k] = (s ? 6 : 3) + gh_i;
    int gh = s ? ((gh_i + 4) % 5) : (gh_i + 1);
    g9s[k] = __builtin_amdgcn_readfirstlane((gh * 5 + gw_i) * 9);
  }

#define PV_STORE(OH, OW)                                                   \
  do {                                                                     \
    int e_ = gh_i * 6 + ((OW)-3);                                          \
    const unsigned short* vrow_ = vT + e_ * VP;                            \
    float acc_ = 0.f;                                                      \
    _Pragma("unroll") for (int d_ = 0; d_ < 9; ++d_) acc_ =                \
        fmaf(a2[d_], bf2f(vrow_[ch + d_]), acc_);                          \
    acc_ *= inv_s;                                                         \
    if ((OH) < 6 && (OW) < 6)                                              \
      acc_ += hi_f(xk1[XP * (((OH) + 3) * 9 + ((OW) + 3)) + 4 + ch]);      \
    if (valid_inst) outb[(OH)*9 + (OW)] = acc_;                            \
  } while (0)

  // prologue gather (instance 0), then 1-deep prefetch pipeline
  unsigned int ga[9];
#pragma unroll
  for (int q = 0; q < 9; ++q)
    ga[q] = xk1[(int)pixtab[g9s[0] + tq[q]] + cq[q]];

#pragma unroll
  for (int k = 0; k < 4; ++k) {
    unsigned int gb[9];
    if (k < 3) {
#pragma unroll
      for (int q = 0; q < 9; ++q)
        gb[q] = xk1[(int)pixtab[g9s[k + 1] + tq[q]] + cq[q]];
    }
    const bool valid_inst = valids[k];
    const int g9 = g9s[k];
    const int gh_i = ghis[k], gw_i = gwis[k], oh = ohs[k];

    __builtin_amdgcn_s_setprio(1);
    // w1 -> folded BN -> ReLU  (x-part lo16, k1-part hi16 of same dword)
    float r[9];
#pragma unroll
    for (int o = 0; o < 9; ++o) {
      int m = g9 + o;
      const float* w1m = w1 + m * 18;
      float a = 0.f;
#pragma unroll
      for (int q = 0; q < 9; ++q) {
        a = fmaf(w1m[q], lo_f(ga[q]), a);
        a = fmaf(w1m[9 + q], hi_f(ga[q]), a);
      }
      float2 bn = bnf[m];
      a = fmaf(a, bn.x, bn.y);
      r[o] = fmaxf(a, 0.f);
    }

    // w2 + b2 -> softmax (registers)
    float a2[9], mx = -1e30f;
#pragma unroll
    for (int d = 0; d < 9; ++d) {
      int m = g9 + d;
      const float* w2m = w2 + m * 9;
      float a = b2[m];
#pragma unroll
      for (int o = 0; o < 9; ++o) a = fmaf(w2m[o], r[o], a);
      a2[d] = a;
      mx = fmaxf(mx, a);
    }
    float ssum = 0.f;
#pragma unroll
    for (int d = 0; d < 9; ++d) {
      a2[d] = __expf(a2[d] - mx);
      ssum += a2[d];
    }
    float inv_s = __builtin_amdgcn_rcpf(ssum);
    __builtin_amdgcn_s_setprio(0);

    // PV + k1-add + store; gw==1 serves both ow=3 and ow=8
    int ow0 = (gw_i == 0) ? 7 : (gw_i + 2);
    PV_STORE(oh, ow0);
    if (gw_i == 1) PV_STORE(oh, 8);

    if (k < 3) {
#pragma unroll
      for (int q = 0; q < 9; ++q) ga[q] = gb[q];
    }
  }
#undef PV_STORE

  // ---- epilogue: non-PV output pixels (k1 from hi16)
  if (s == 0) {
    if (s4 < 3) {
      int oh = s4;  // rows 0..2: k1 where ow<6, else 0
#pragma unroll
      for (int ow = 0; ow < 9; ++ow) {
        float v2 = 0.f;
        if (ow < 6)
          v2 = hi_f(xk1[XP * ((oh + 3) * 9 + (ow + 3)) + 4 + ch]);
        outb[oh * 9 + ow] = v2;
      }
    } else {
      // rows 3..5, cols 0..2: k1-only
#pragma unroll
      for (int r0 = 0; r0 < 3; ++r0) {
        int oh = 3 + r0;
#pragma unroll
        for (int ow = 0; ow < 3; ++ow)
          outb[oh * 9 + ow] =
              hi_f(xk1[XP * ((oh + 3) * 9 + (ow + 3)) + 4 + ch]);
      }
    }
  } else if (s4 < 3) {
    int oh = 6 + s4;  // rows 6..8, cols 0..2: zero
    outb[oh * 9 + 0] = 0.f;
    outb[oh * 9 + 1] = 0.f;
    outb[oh * 9 + 2] = 0.f;
  }
}

extern "C" void kernel_launch(void* const* d_in, const int* in_sizes, int n_in,
                              void* d_out, int out_size, void* d_ws, size_t ws_size,
                              hipStream_t stream) {
  const float* x     = (const float*)d_in[0];
  const float* wk    = (const float*)d_in[1];
  const float* bk    = (const float*)d_in[2];
  const float* w1    = (const float*)d_in[3];
  const float* gamma = (const float*)d_in[4];
  const float* beta  = (const float*)d_in[5];
  const float* mean  = (const float*)d_in[6];
  const float* var   = (const float*)d_in[7];
  const float* w2    = (const float*)d_in[8];
  const float* b2    = (const float*)d_in[9];
  const float* wv    = (const float*)d_in[10];
  const float* bv    = (const float*)d_in[11];
  float* out = (float*)d_out;

  hipLaunchKernelGGL(semca_fused, dim3(256), dim3(1024), 0, stream,
                     x, wk, bk, w1, gamma, beta, mean, var, w2, b2, wv, bv, out);
}

// Round 5
// 27.614 us; speedup vs baseline: 1.0522x; 1.0522x over previous
//
#include <hip/hip_runtime.h>

#define C 256
#define HW 81
#define PITCH 292   // ushorts per pixel row: [4 pad][256 ch][32 pad] (even dword pitch)
#define PITCHD 146  // dwords per pixel row; 146%32=18 -> gather tap bases ~4-apart
#define ZROW 81     // zeroed row index for invalid gather taps

__device__ __forceinline__ float lo_f(unsigned int d) {
  union { unsigned int i; float f; } c; c.i = d << 16; return c.f;
}
__device__ __forceinline__ float hi_f(unsigned int d) {
  union { unsigned int i; float f; } c; c.i = d & 0xffff0000u; return c.f;
}
__device__ __forceinline__ float bf2f(unsigned short u) {
  union { unsigned int i; float f; } c; c.i = ((unsigned int)u) << 16; return c.f;
}
__device__ __forceinline__ unsigned short f2bf(float f) {
  union { float f; unsigned int i; } c; c.f = f;
  return (unsigned short)((c.i + 0x7fffu + ((c.i >> 16) & 1u)) >> 16);
}
__device__ __forceinline__ unsigned int pack2(float a, float b) {
  return (unsigned int)f2bf(a) | ((unsigned int)f2bf(b) << 16);
}

// ---------------------------------------------------------------------------
// Fully fused SeMCA. Block = (b, s): s=0 -> output rows 0..5, s=1 -> rows 6..8.
// 1024 threads = 4 instance-slots x 256 channels. 2 barriers.
// R5 (theory: phase-0 critical path — loads strung out behind pack/write and
// division chains). Changes vs R3 (27.73us), phase 0 ONLY:
//  - all 21 x global loads issued FIRST into registers; addresses via an
//    incremental (chp,p) walk (no per-call magic-division chain);
//  - pad zeroing, pixtab/bnf tables, wv/bv preloads execute under the load
//    shadow; pack+LDS-write happens once at the end (single drain);
//  - phases 1a/1b/2/epilogue byte-identical to R3.
// ---------------------------------------------------------------------------
__global__ __launch_bounds__(1024) void semca_fused(
    const float* __restrict__ x, const float* __restrict__ wk,
    const float* __restrict__ bk, const float* __restrict__ w1,
    const float* __restrict__ gamma, const float* __restrict__ beta,
    const float* __restrict__ mean, const float* __restrict__ var,
    const float* __restrict__ w2, const float* __restrict__ b2,
    const float* __restrict__ wv, const float* __restrict__ bv,
    float* __restrict__ out) {
  __shared__ unsigned short xT[82 * PITCH];   // 47,888 B (row 81 = zeros)
  __shared__ unsigned short k1T[82 * PITCH];  // 47,888 B (row 81 = zeros)
  __shared__ unsigned short vT[18 * PITCH];   // 10,512 B
  __shared__ unsigned short pixtab[228];      //    456 B (premultiplied by PITCH)
  __shared__ float2 bnf[225];                 //  1,800 B  (~106 KiB total)

  const int blk = blockIdx.x;
  const int b = (blk & 7) * 16 + ((blk >> 3) & 15);  // XCD-paired, bijective
  const int s = blk >> 7;
  const int tid = threadIdx.x;
  const float* xb = x + (size_t)b * (C * HW);

  unsigned int* xTd = (unsigned int*)xT;
  unsigned int* k1Td = (unsigned int*)k1T;
  unsigned int* vTd = (unsigned int*)vT;

  // ---- phase 0a: issue ALL x loads first (registers), incremental walk
  float xe[11], xo[11];
  int adr[11];
  {
    int chp = tid / HW;            // single division
    int p = tid - chp * HW;
#pragma unroll
    for (int rep = 0; rep < 10; ++rep) {
      const float* base = xb + (2 * chp) * HW + p;
      xe[rep] = base[0];
      xo[rep] = base[HW];
      adr[rep] = PITCHD * p + 2 + chp;
      chp += 12;                   // advance f by 1024 = 12*81 + 52
      p += 52;
      if (p >= HW) { p -= HW; chp += 1; }
    }
    if (tid < 128) {               // tail item f = 10240 + tid
      int f = 10240 + tid;
      int c2 = f / HW, p2 = f - c2 * HW;
      xe[10] = xb[2 * c2 * HW + p2];
      xo[10] = xb[(2 * c2 + 1) * HW + p2];
      adr[10] = PITCHD * p2 + 2 + c2;
    }
  }

  // ---- phase 0b: independent work under the load shadow
  for (int t = tid; t < 810; t += 1024) {  // x channel-pad zeros
    int p = t / 10, k2 = t - (t / 10) * 10;
    xT[p * PITCH + ((k2 < 4) ? k2 : (256 + k2))] = 0;
  }
  if (tid < PITCHD) {                      // zero row 81 of xT and k1T
    xTd[PITCHD * ZROW + tid] = 0;
    k1Td[PITCHD * ZROW + tid] = 0;
  }
  for (int t = tid; t < 225; t += 1024) {  // pixtab (premul) + folded BN
    int g = t / 9, tap = t - (t / 9) * 9;
    int kh = tap / 3, kw = tap - kh * 3;
    int h = kh * 5 + g / 5, w = kw * 5 + (g - (g / 5) * 5);
    pixtab[t] = (h < 9 && w < 9) ? (unsigned short)((h * 9 + w) * PITCH)
                                 : (unsigned short)(ZROW * PITCH);
    float inv = gamma[t] * rsqrtf(var[t] + 1e-5f);
    bnf[t] = make_float2(inv, beta[t] - mean[t] * inv);
  }

  // hoisted phase-1b weights: chv fixed per thread -> registers
  const int chv = tid & 127;
  float wv_e[9], wv_o[9];
#pragma unroll
  for (int t = 0; t < 9; ++t) {
    wv_e[t] = wv[(2 * chv) * 9 + t];
    wv_o[t] = wv[(2 * chv + 1) * 9 + t];
  }
  const float bv_e = bv[2 * chv], bv_o = bv[2 * chv + 1];

  // ---- phase 0c: pack + LDS write (single drain of the x loads)
#pragma unroll
  for (int rep = 0; rep < 10; ++rep) xTd[adr[rep]] = pack2(xe[rep], xo[rep]);
  if (tid < 128) xTd[adr[10]] = pack2(xe[10], xo[10]);

  __syncthreads();

  // ---- phase 1a: k1[p][ch] = sum_j x[p][ch+j-4]*wk[p][j] + bk[p]
  // width-4: channels 4u..4u+3 need ushorts 4u..4u+11 (ch-4 halo via left
  // pad) = dwords 2u..2u+5 from the ROW BASE -> 3x ds_read_b64, 1x b64 write.
  {
    auto k1fn = [&](int f) {
      int p = __builtin_amdgcn_readfirstlane(f >> 6);
      int u = f & 63;  // channel quad index
      const uint2* wrow2 = (const uint2*)(xTd + PITCHD * p);
      uint2 q0 = wrow2[u], q1 = wrow2[u + 1], q2 = wrow2[u + 2];
      float e[12] = {lo_f(q0.x), hi_f(q0.x), lo_f(q0.y), hi_f(q0.y),
                     lo_f(q1.x), hi_f(q1.x), lo_f(q1.y), hi_f(q1.y),
                     lo_f(q2.x), hi_f(q2.x), lo_f(q2.y), hi_f(q2.y)};
      const float* wkp = wk + p * 9;  // scalar loads (p uniform)
      float bkp = bk[p];
      float c0 = bkp, c1 = bkp, c2 = bkp, c3 = bkp;
#pragma unroll
      for (int j = 0; j < 9; ++j) {
        float wj = wkp[j];
        c0 = fmaf(wj, e[j], c0);
        c1 = fmaf(wj, e[j + 1], c1);
        c2 = fmaf(wj, e[j + 2], c2);
        c3 = fmaf(wj, e[j + 3], c3);
      }
      *(uint2*)(k1Td + PITCHD * p + 2 + 2 * u) =
          make_uint2(pack2(c0, c1), pack2(c2, c3));
    };
#pragma unroll
    for (int rep = 0; rep < 5; ++rep) k1fn(tid + rep * 1024);
    if (tid < 64) k1fn(5120 + tid);
  }

  // ---- phase 1b: v (3x3 depthwise) at the 18 pixels this half needs
  {
    auto vfn = [&](int f) {
      int e = __builtin_amdgcn_readfirstlane(f >> 7);  // 0..17 uniform
      int r0 = e / 6;
      int i = s * 3 + r0;  // v-pixel row 0..5
      int j = e - r0 * 6;  // v-pixel col 0..5
      float a_e = bv_e, a_o = bv_o;
#pragma unroll
      for (int di = 0; di < 3; ++di) {
        int ii = i + di - 1;
        if (ii < 0) continue;  // ii <= 6 < 9 always
#pragma unroll
        for (int dj = 0; dj < 3; ++dj) {
          int jj = j + dj - 1;
          if (jj < 0) continue;  // jj <= 6 < 9 always
          unsigned int d = xTd[PITCHD * (ii * 9 + jj) + 2 + chv];
          int t = di * 3 + dj;
          a_e = fmaf(lo_f(d), wv_e[t], a_e);
          a_o = fmaf(hi_f(d), wv_o[t], a_o);
        }
      }
      vTd[PITCHD * e + 2 + chv] = pack2(a_e, a_o);
    };
#pragma unroll
    for (int rep = 0; rep < 2; ++rep) vfn(tid + rep * 1024);
    if (tid < 256) vfn(2048 + tid);
  }
  if (tid < 180) {  // vT channel-pad zeros
    int e = tid / 10, k2 = tid - (tid / 10) * 10;
    vT[e * PITCH + ((k2 < 4) ? k2 : (256 + k2))] = 0;
  }
  __syncthreads();

  // ---- phase 2: 15 deduped instances; 4 slots x 4 unrolled iterations
  const int s4 = tid >> 8;  // slot 0..3 (wave-uniform)
  const int ch = tid & 255;
  const int ci0 = ch / 9;
  const int tap0 = ch - ci0 * 9;
  float* outb = out + ((size_t)b * C + ch) * HW;

  // per-lane gather walk is instance-invariant: hoist out of the k-loop
  int tq[9], cq[9];
  {
    int ci = ci0, tap = tap0;
#pragma unroll
    for (int q = 0; q < 9; ++q) {
      tq[q] = tap;
      cq[q] = 4 + ci;
      tap += 4;
      ci += 28;
      if (tap >= 9) { tap -= 9; ci += 1; }
    }
  }

#define PV_STORE(OH, OW)                                                   \
  do {                                                                     \
    int e_ = gh_i * 6 + ((OW)-3);                                          \
    const unsigned short* vrow_ = vT + e_ * PITCH;                         \
    float acc_ = 0.f;                                                      \
    _Pragma("unroll") for (int d_ = 0; d_ < 9; ++d_) acc_ =                \
        fmaf(a2[d_], bf2f(vrow_[ch + d_]), acc_);                          \
    acc_ *= inv_s;                                                         \
    if ((OH) < 6 && (OW) < 6)                                              \
      acc_ += bf2f(k1T[(((OH) + 3) * 9 + ((OW) + 3)) * PITCH + 4 + ch]);   \
    if (valid_inst) outb[(OH)*9 + (OW)] = acc_;                            \
  } while (0)

#pragma unroll
  for (int k = 0; k < 4; ++k) {
    int idx = s4 * 4 + k;
    const bool valid_inst = (idx < 15);
    if (!valid_inst) idx = 14;  // dummy recomputes a real instance, no store
    int gh_i = idx / 5, gw_i = idx - (idx / 5) * 5;
    int oh = (s ? 6 : 3) + gh_i;
    int gh = s ? ((gh_i + 4) % 5) : (gh_i + 1);
    int g9 = __builtin_amdgcn_readfirstlane((gh * 5 + gw_i) * 9);

    // kq gather via premultiplied pixtab (zero-row kills validity selects)
    float kq[18];
#pragma unroll
    for (int q = 0; q < 9; ++q) {
      int off = (int)pixtab[g9 + tq[q]] + cq[q];
      kq[q] = bf2f(xT[off]);
      kq[9 + q] = bf2f(k1T[off]);
    }

    __builtin_amdgcn_s_setprio(1);
    // w1 -> folded BN -> ReLU
    float r[9];
#pragma unroll
    for (int o = 0; o < 9; ++o) {
      int m = g9 + o;
      const float* w1m = w1 + m * 18;
      float a = 0.f;
#pragma unroll
      for (int i2 = 0; i2 < 18; ++i2) a = fmaf(w1m[i2], kq[i2], a);
      float2 bn = bnf[m];
      a = fmaf(a, bn.x, bn.y);
      r[o] = fmaxf(a, 0.f);
    }

    // w2 + b2 -> softmax (registers)
    float a2[9], mx = -1e30f;
#pragma unroll
    for (int d = 0; d < 9; ++d) {
      int m = g9 + d;
      const float* w2m = w2 + m * 9;
      float a = b2[m];
#pragma unroll
      for (int o = 0; o < 9; ++o) a = fmaf(w2m[o], r[o], a);
      a2[d] = a;
      mx = fmaxf(mx, a);
    }
    float ssum = 0.f;
#pragma unroll
    for (int d = 0; d < 9; ++d) {
      a2[d] = __expf(a2[d] - mx);
      ssum += a2[d];
    }
    float inv_s = __builtin_amdgcn_rcpf(ssum);
    __builtin_amdgcn_s_setprio(0);

    // PV + k1-add + store; gw==1 serves both ow=3 and ow=8
    int ow0 = (gw_i == 0) ? 7 : (gw_i + 2);
    PV_STORE(oh, ow0);
    if (gw_i == 1) PV_STORE(oh, 8);
  }
#undef PV_STORE

  // ---- epilogue: non-PV output pixels
  if (s == 0) {
    if (s4 < 3) {
      int oh = s4;  // rows 0..2: k1 where ow<6, else 0
#pragma unroll
      for (int ow = 0; ow < 9; ++ow) {
        float v2 = 0.f;
        if (ow < 6)
          v2 = bf2f(k1T[((oh + 3) * 9 + (ow + 3)) * PITCH + 4 + ch]);
        outb[oh * 9 + ow] = v2;
      }
    } else {
      // rows 3..5, cols 0..2: k1-only
#pragma unroll
      for (int r0 = 0; r0 < 3; ++r0) {
        int oh = 3 + r0;
#pragma unroll
        for (int ow = 0; ow < 3; ++ow)
          outb[oh * 9 + ow] =
              bf2f(k1T[((oh + 3) * 9 + (ow + 3)) * PITCH + 4 + ch]);
      }
    }
  } else if (s4 < 3) {
    int oh = 6 + s4;  // rows 6..8, cols 0..2: zero
    outb[oh * 9 + 0] = 0.f;
    outb[oh * 9 + 1] = 0.f;
    outb[oh * 9 + 2] = 0.f;
  }
}

extern "C" void kernel_launch(void* const* d_in, const int* in_sizes, int n_in,
                              void* d_out, int out_size, void* d_ws, size_t ws_size,
                              hipStream_t stream) {
  const float* x     = (const float*)d_in[0];
  const float* wk    = (const float*)d_in[1];
  const float* bk    = (const float*)d_in[2];
  const float* w1    = (const float*)d_in[3];
  const float* gamma = (const float*)d_in[4];
  const float* beta  = (const float*)d_in[5];
  const float* mean  = (const float*)d_in[6];
  const float* var   = (const float*)d_in[7];
  const float* w2    = (const float*)d_in[8];
  const float* b2    = (const float*)d_in[9];
  const float* wv    = (const float*)d_in[10];
  const float* bv    = (const float*)d_in[11];
  float* out = (float*)d_out;

  hipLaunchKernelGGL(semca_fused, dim3(256), dim3(1024), 0, stream,
                     x, wk, bk, w1, gamma, beta, mean, var, w2, b2, wv, bv, out);
}